// Round 10
// baseline (450.218 us; speedup 1.0000x reference)
//
#include <hip/hip_runtime.h>
#include <hip/hip_bf16.h>

#define BB 2
#define NN 8192
#define SPL 16
#define NPTS (BB*NN)

// ---- workspace layout (units: 4-byte words) ----
// Base layout (26.5 MB) unchanged from R4/R19. Wide mode (R20, proven -14%)
// adds part2 (16 MB) after the base region when ws_size permits: 32-segment
// KNN split -> 2048 A-blocks.
#define POS4_OFF 0u                     /* 65,536 w float4 (x,y,z,0) */
#define PART_OFF 65536u                 /* lists 0..255: [256][NPTS] 16MB */
#define IDX_OFF  4259840u               /* 262,144 w */
#define WT_OFF   4521984u               /* 4 mats x 4096 bf16 = 8,192 w */
#define QB_OFF   4530176u               /* 1,048,576 w */
#define KVB_OFF  5578752u               /* 1,048,576 w packed bf16 k|v */
#define PART2_OFF 6627328u              /* lists 256..511 (wide mode only) */
#define WIDE_WORDS (PART2_OFF + 4194304u)

typedef __attribute__((ext_vector_type(8))) short bf16x8;
typedef __attribute__((ext_vector_type(4))) float f32x4;

__device__ __forceinline__ unsigned umn(unsigned a, unsigned b) {
#if __has_builtin(__builtin_elementwise_min)
  return __builtin_elementwise_min(a, b);
#else
  return a < b ? a : b;
#endif
}
__device__ __forceinline__ unsigned umx(unsigned a, unsigned b) {
#if __has_builtin(__builtin_elementwise_max)
  return __builtin_elementwise_max(a, b);
#else
  return a < b ? b : a;
#endif
}

__device__ inline unsigned short f2bf(float x) {
  __hip_bfloat16 b = __float2bfloat16(x);
  return *(unsigned short*)&b;
}

// column-block rotate swizzle for conflict-free ds_read_b128 fragments
#define HCOL(c, j) ((((((c) >> 3) + (j)) & 7) << 3) | ((c) & 7))

// per-batch distance + OEMS-16 sort + merge into m[] (R12-proven math, exact)
#define SORTB(CC, JBASE)                                                    \
  do {                                                                      \
    unsigned b[16];                                                         \
    _Pragma("unroll")                                                       \
    for (int i = 0; i < 16; i++) {                                          \
      const float cx = CC[(3 * i) >> 2][(3 * i) & 3];                       \
      const float cy = CC[(3 * i + 1) >> 2][(3 * i + 1) & 3];               \
      const float cz = CC[(3 * i + 2) >> 2][(3 * i + 2) & 3];               \
      float dx = cx - qx, dy = cy - qy, dz = cz - qz;                       \
      float d2 = fmaf(dx, dx, fmaf(dy, dy, dz * dz));                       \
      b[i] = (__float_as_uint(d2) & 0xFFFFE000u) |                          \
             (jb + (unsigned)((JBASE) + i));                                \
    }                                                                       \
    _Pragma("unroll")                                                       \
    for (int cc2 = 0; cc2 < 63; cc2++) {                                    \
      const int x = OE[cc2][0], y = OE[cc2][1];                             \
      unsigned lo = umn(b[x], b[y]);                                        \
      unsigned hi = umx(b[x], b[y]);                                        \
      b[x] = hi; b[y] = lo;                                                 \
    }                                                                       \
    _Pragma("unroll")                                                       \
    for (int i = 0; i < 16; i++) m[i] = umn(m[i], b[i]);                    \
    _Pragma("unroll")                                                       \
    for (int d = 8; d; d >>= 1) {                                           \
      _Pragma("unroll")                                                     \
      for (int i = 0; i < 16; i++) {                                        \
        if ((i & d) == 0) {                                                 \
          const int l = i | d;                                              \
          unsigned lo = umn(m[i], m[l]);                                    \
          unsigned hi = umx(m[i], m[l]);                                    \
          m[i] = lo; m[l] = hi;                                             \
        }                                                                   \
      }                                                                     \
    }                                                                       \
  } while (0)

// ============================ MEGA1: KNN + qkv/pos4 + wt (role-split) =========
// Role order: B [0,512) | C [512,576) | A [576, 576+64*NSEG).
// R22: R21's 16KB LDS kept, PLUS __launch_bounds__(256,8) to force VGPR<=64.
// R21 lesson (counter-proven): role-B restructure pushed VGPR 60->72, crossing
// the 64-VGPR cliff (waves/SIMD halves at 64/128/256) -> 4 blocks/CU despite
// 16KB LDS; dur 81->105 (~6/4 TLP ratio). lb(256,8) pins the allocator under
// the cliff; any spill lands in role B (512 blocks, overlapped) while role A
// (~60 VGPR natural) gets 8 blocks/CU vs R20's 6.
template <int NSEG>
__global__ __launch_bounds__(256, 8) void mega1_t(
    const float* __restrict__ pos, const float* __restrict__ feat,
    const float* __restrict__ emb_w, const float* __restrict__ emb_b,
    const float* __restrict__ wq, const float* __restrict__ wk,
    const float* __restrict__ wv,
    const float* __restrict__ pe_w2, const float* __restrict__ at_w1,
    const float* __restrict__ at_w2, const float* __restrict__ out_w,
    float* __restrict__ ws)
{
  __shared__ __align__(16) float smem[4096];   // 16 KB: wl[2048] | xl[2048]
  const int tid = threadIdx.x;
  const int bx = blockIdx.x;
  float* pos4 = ws + POS4_OFF;
  unsigned* part = (unsigned*)ws + PART_OFF;
  unsigned* part2 = (unsigned*)ws + PART2_OFF;
  float* qg = ws + QB_OFF;
  unsigned* kvp = (unsigned*)ws + KVB_OFF;
  constexpr int CANDN = NN / NSEG;

  if (bx >= 576) {
    // ---------------- role A: KNN (LDS-staged candidates, batch-16 OEMS) ----
    constexpr int OE[63][2] = {
      {0,1},{2,3},{4,5},{6,7},{8,9},{10,11},{12,13},{14,15},
      {0,2},{1,3},{4,6},{5,7},{8,10},{9,11},{12,14},{13,15},
      {1,2},{5,6},{9,10},{13,14},
      {0,4},{1,5},{2,6},{3,7},{8,12},{9,13},{10,14},{11,15},
      {2,4},{3,5},{10,12},{11,13},
      {1,2},{3,4},{5,6},{9,10},{11,12},{13,14},
      {0,8},{1,9},{2,10},{3,11},{4,12},{5,13},{6,14},{7,15},
      {4,8},{5,9},{6,10},{7,11},
      {2,4},{3,5},{6,8},{7,9},{10,12},{11,13},
      {1,2},{3,4},{5,6},{7,8},{9,10},{11,12},{13,14}
    };
    const int aIdx = bx - 576;
    const int g = (aIdx & 63) * 256 + tid;
    const int s = aIdx >> 6;                  // [0, NSEG)
    const int bu = __builtin_amdgcn_readfirstlane(g >> 13);
    const float qx = pos[g * 3 + 0], qy = pos[g * 3 + 1], qz = pos[g * 3 + 2];
    const unsigned jb = (unsigned)(s * CANDN);
    // stage this block's CANDN-candidate segment into LDS (coalesced f32x4)
    {
      const f32x4* segp = (const f32x4*)(pos + (bu * NN + s * CANDN) * 3);
      f32x4* cl4w = (f32x4*)smem;
      for (int i = tid; i < (CANDN * 3) / 4; i += 256) cl4w[i] = segp[i];
    }
    __syncthreads();
    const f32x4* cl4 = (const f32x4*)smem;
    unsigned m[16];
#pragma unroll
    for (int i = 0; i < 16; i++) m[i] = 0xFFFFFFFFu;
    f32x4 ca[12], cb[12];
#pragma unroll
    for (int i = 0; i < 12; i++) ca[i] = cl4[i];          // batch 0
    for (int j0 = 0; j0 < CANDN; j0 += 32) {
      const int b1 = ((j0 >> 4) + 1) * 12;                // batch j0+16
#pragma unroll
      for (int i = 0; i < 12; i++) cb[i] = cl4[b1 + i];
      SORTB(ca, j0);
      const int b2 = ((j0 + 32 < CANDN) ? ((j0 >> 4) + 2) : ((j0 >> 4) + 1)) * 12;
#pragma unroll
      for (int i = 0; i < 12; i++) ca[i] = cl4[b2 + i];   // batch j0+32 (clamped)
      SORTB(cb, j0 + 16);
    }
#pragma unroll
    for (int i = 0; i < 16; i++) {
      const unsigned L = (unsigned)(s * 16 + i);          // list index
      unsigned* dst = (L < 256u) ? (part + L * NPTS) : (part2 + (L - 256u) * NPTS);
      dst[(unsigned)g] = m[i];
    }
  } else if (bx < 512) {
    // ---------------- role B: pos4 + emb + qkv, half-staged weights ---------
    // Two 32-row halves per matrix; c = h*32+cc runs 0..63 in order ->
    // accumulation bit-identical (R21-verified, absmax unchanged).
    float* wl = smem;            // 2048 floats (8 KB)
    float* xl = smem + 2048;     // 2048 floats (8 KB)
    const int vb = bx;
    const int col = tid & 63;
    const int rg = tid >> 6;
    const int row0 = vb * 32 + rg * 8;
    const int rowu = __builtin_amdgcn_readfirstlane(row0);
    if (tid < 32) {              // pos4 staging: 32 points/block
      const int p = vb * 32 + tid;
      float x = pos[p * 3 + 0], y = pos[p * 3 + 1], z = pos[p * 3 + 2];
      float4 v = {x, y, z, 0.f};
      ((float4*)pos4)[p] = v;
    }
    // ---- emb: x = feat @ emb_w + emb_b ----
    {
      float acc[8];
      float bias = emb_b[col];
#pragma unroll
      for (int r = 0; r < 8; r++) acc[r] = bias;
      for (int h = 0; h < 2; h++) {
        __syncthreads();
        for (int i = tid; i < 2048; i += 256) wl[i] = emb_w[h * 2048 + i];
        __syncthreads();
        for (int cc = 0; cc < 32; cc++) {
          float w = wl[cc * 64 + col];
          const float* fp = feat + rowu * 64 + h * 32 + cc;  // uniform scalar
#pragma unroll
          for (int r = 0; r < 8; r++) acc[r] = fmaf(fp[r * 64], w, acc[r]);
        }
      }
#pragma unroll
      for (int r = 0; r < 8; r++) xl[(rg * 8 + r) * 64 + col] = acc[r];
    }
    // ---- q ----
    {
      float aq[8];
#pragma unroll
      for (int r = 0; r < 8; r++) aq[r] = 0.f;
      for (int h = 0; h < 2; h++) {
        __syncthreads();
        for (int i = tid; i < 2048; i += 256) wl[i] = wq[h * 2048 + i];
        __syncthreads();
        for (int cc = 0; cc < 32; cc++) {
          float w = wl[cc * 64 + col];
#pragma unroll
          for (int r = 0; r < 8; r++)
            aq[r] = fmaf(xl[(rg * 8 + r) * 64 + h * 32 + cc], w, aq[r]);
        }
      }
#pragma unroll
      for (int r = 0; r < 8; r++) qg[(row0 + r) * 64 + col] = aq[r];
    }
    // ---- k (kept in regs) ----
    float ak[8];
    {
#pragma unroll
      for (int r = 0; r < 8; r++) ak[r] = 0.f;
      for (int h = 0; h < 2; h++) {
        __syncthreads();
        for (int i = tid; i < 2048; i += 256) wl[i] = wk[h * 2048 + i];
        __syncthreads();
        for (int cc = 0; cc < 32; cc++) {
          float w = wl[cc * 64 + col];
#pragma unroll
          for (int r = 0; r < 8; r++)
            ak[r] = fmaf(xl[(rg * 8 + r) * 64 + h * 32 + cc], w, ak[r]);
        }
      }
    }
    // ---- v + pack ----
    {
      float av[8];
#pragma unroll
      for (int r = 0; r < 8; r++) av[r] = 0.f;
      for (int h = 0; h < 2; h++) {
        __syncthreads();
        for (int i = tid; i < 2048; i += 256) wl[i] = wv[h * 2048 + i];
        __syncthreads();
        for (int cc = 0; cc < 32; cc++) {
          float w = wl[cc * 64 + col];
#pragma unroll
          for (int r = 0; r < 8; r++)
            av[r] = fmaf(xl[(rg * 8 + r) * 64 + h * 32 + cc], w, av[r]);
        }
      }
#pragma unroll
      for (int r = 0; r < 8; r++)
        kvp[(row0 + r) * 64 + col] =
            ((unsigned)f2bf(av[r]) << 16) | (unsigned)f2bf(ak[r]);
    }
  } else {
    // ---------------- role C: wt bf16-T staging ----------------
    const int t = (bx - 512) * 256 + tid;    // wt[m*4096+f*64+c]=W_m[c*64+f]
    const float* s;
    switch (t >> 12) {
      case 0: s = pe_w2; break;
      case 1: s = at_w1; break;
      case 2: s = at_w2; break;
      default: s = out_w; break;
    }
    const int idx = t & 4095, f = idx >> 6, c = idx & 63;
    ((unsigned short*)(ws + WT_OFF))[t] = f2bf(s[c * 64 + f]);
  }
}

// ============================ S3: merge NSEG sorted 16-lists (coalesced) ======
// R16/R18: keep standalone (fusion into s4 regressed twice).
// R22: 64x256 -> 256x64 grid. Old shape put 4 waves on each of only 64 CUs
// (192 CUs idle, VGPR=256 caps 2 waves/SIMD anyway). 64-thread blocks spread
// the same 16384 threads across all 256 CUs. Per-thread code & coalescing
// (64 consecutive g per wave) unchanged.
template <int NSEG>
__global__ __launch_bounds__(64) void s3_merge_t(const float* __restrict__ ws_ro,
                                                 int* __restrict__ knn_idx)
{
  const unsigned* part = (const unsigned*)ws_ro + PART_OFF;
  const unsigned* part2 = (const unsigned*)ws_ro + PART2_OFF;
  const int g = blockIdx.x * 64 + threadIdx.x;
  unsigned run[16];
#pragma unroll
  for (int i = 0; i < 16; i++) run[i] = part[i * NPTS + g];
#pragma unroll
  for (int l = 1; l < NSEG; l++) {
#pragma unroll
    for (int i = 0; i < 16; i++) {
      const int L = l * 16 + 15 - i;
      const unsigned v = (L < 256) ? part[L * NPTS + g]
                                   : part2[(L - 256) * NPTS + g];
      run[i] = umn(run[i], v);
    }
#pragma unroll
    for (int d = 8; d; d >>= 1) {
#pragma unroll
      for (int i = 0; i < 16; i++) {
        if ((i & d) == 0) {
          const int l2 = i | d;
          unsigned lo = umn(run[i], run[l2]);
          unsigned hi = umx(run[i], run[l2]);
          run[i] = lo; run[l2] = hi;
        }
      }
    }
  }
  const int base = (g >> 13) * NN;
  int outv[16];
#pragma unroll
  for (int i = 0; i < 16; i++) outv[i] = base + (int)(run[i] & 0x1FFFu);
  int4* o = (int4*)(knn_idx + g * 16);
  o[0] = make_int4(outv[0], outv[1], outv[2], outv[3]);
  o[1] = make_int4(outv[4], outv[5], outv[6], outv[7]);
  o[2] = make_int4(outv[8], outv[9], outv[10], outv[11]);
  o[3] = make_int4(outv[12], outv[13], outv[14], outv[15]);
}

// ============================ S4: MFMA fused posenc/attn/softmax/out ==========
// R19-proven EXACT (won -12 us): mv weights in 24KB swizzled LDS, not 96 VGPRs.
__device__ inline void mvl(const unsigned short* hm, const unsigned short* wl,
                           int mat, const float bias[4], int ln, int s0, int s1,
                           f32x4 acc[4])
{
  bf16x8 a0 = *(const bf16x8*)(hm + ln * 64 + s0);
  bf16x8 a1 = *(const bf16x8*)(hm + ln * 64 + s1);
#pragma unroll
  for (int t = 0; t < 4; t++) {
    const unsigned short* wr = wl + mat * 4096 + (t * 16 + ln) * 64;
    bf16x8 B0 = *(const bf16x8*)(wr + s0);
    bf16x8 B1 = *(const bf16x8*)(wr + s1);
    f32x4 a = {bias[t], bias[t], bias[t], bias[t]};
    a = __builtin_amdgcn_mfma_f32_16x16x32_bf16(a0, B0, a, 0, 0, 0);
    a = __builtin_amdgcn_mfma_f32_16x16x32_bf16(a1, B1, a, 0, 0, 0);
    acc[t] = a;
  }
}

__global__ __launch_bounds__(256, 2) void s4_attn(
    const float* __restrict__ ws_ro, const float* __restrict__ feat,
    const float* __restrict__ pe_w1, const float* __restrict__ pe_b1,
    const float* __restrict__ pe_b2, const float* __restrict__ at_b1,
    const float* __restrict__ at_b2, const float* __restrict__ out_b,
    const int* __restrict__ knn, float* __restrict__ out)
{
  __shared__ unsigned short hma[4][1024];       // per-wave 16x64 bf16 h (8 KB)
  __shared__ unsigned short resm[1024];         // 16 points x 64 bf16   (2 KB)
  __shared__ __align__(16) unsigned short wlds[12288];  // 3 mats swizzled
  const float* pos4 = ws_ro + POS4_OFF;
  const float* qg = ws_ro + QB_OFF;
  const unsigned* kvp = (const unsigned*)ws_ro + KVB_OFF;
  const unsigned short* wt = (const unsigned short*)(ws_ro + WT_OFF);

  const int tid = threadIdx.x;
  const int wid = tid >> 6, lane = tid & 63;
  const int ln = lane & 15, quad = lane >> 4;
  unsigned short* hm = hma[wid];
  const int s0 = ((quad + ln) & 7) << 3;
  const int s1 = ((4 + quad + ln) & 7) << 3;

  // ---- stage mv weight mats 0-2 into LDS with HCOL block swizzle ----
  {
    const bf16x8* src = (const bf16x8*)wt;      // 1536 blocks of 16 B (3 mats)
    bf16x8* dst = (bf16x8*)wlds;
    for (int i = tid; i < 1536; i += 256) {
      const int blk = i & 511, row = blk >> 3, cb = blk & 7;
      dst[(i & ~511) + (row << 3) + ((cb + row) & 7)] = src[i];
    }
  }

  bf16x8 bo[2];
#pragma unroll
  for (int ks = 0; ks < 2; ks++)
    bo[ks] = *(const bf16x8*)(wt + 3 * 4096 + (wid * 16 + ln) * 64 +
                              ks * 32 + quad * 8);

  float pw10 = pe_w1[lane], pw11 = pe_w1[64 + lane], pw12 = pe_w1[128 + lane];
  float pb1 = pe_b1[lane];
  float bpe[4], ba1[4], ba2[4];
#pragma unroll
  for (int t = 0; t < 4; t++) {
    bpe[t] = pe_b2[t * 16 + ln];
    ba1[t] = at_b1[t * 16 + ln];
    ba2[t] = at_b2[t * 16 + ln];
  }
  const float4* pp4 = (const float4*)pos4;

  const int p0 = blockIdx.x * 16 + wid * 4;
  const int ps0 = __builtin_amdgcn_readfirstlane(p0);
  int4 cur[4];
  {
    const int4* ip4 = (const int4*)(knn + ps0 * 16);
#pragma unroll
    for (int u = 0; u < 4; u++) cur[u] = ip4[u];
  }
  __syncthreads();   // wlds ready for all waves

#pragma unroll 1
  for (int pp = 0; pp < 4; pp++) {
    asm volatile("" ::: "memory");   // keep B-frags in LDS, not hoisted regs
    const int p = p0 + pp;
    const int ps = __builtin_amdgcn_readfirstlane(p);
    int jj[16];
#pragma unroll
    for (int u = 0; u < 4; u++) {
      jj[u*4+0] = cur[u].x; jj[u*4+1] = cur[u].y;
      jj[u*4+2] = cur[u].z; jj[u*4+3] = cur[u].w;
    }
    int4 nxt[4];
    {
      const int pn = (pp < 3) ? (ps + 1) : ps;
      const int4* np4 = (const int4*)(knn + pn * 16);
#pragma unroll
      for (int u = 0; u < 4; u++) nxt[u] = np4[u];
    }
    unsigned kvw[4][4];                    // early gathers (hide under mv1)
#pragma unroll
    for (int r = 0; r < 4; r++) {
      const unsigned* kp = kvp + jj[quad * 4 + r] * 64 + ln;
#pragma unroll
      for (int t = 0; t < 4; t++) kvw[r][t] = kp[t * 16];
    }
    float qv[4];
#pragma unroll
    for (int t = 0; t < 4; t++) qv[t] = qg[p * 64 + t * 16 + ln];

    const float4 mp = pp4[ps];
#pragma unroll
    for (int j = 0; j < 16; j++) {
      const float4 np = pp4[jj[j]];
      float h1 = fmaf(np.z - mp.z, pw12,
                 fmaf(np.y - mp.y, pw11,
                 fmaf(np.x - mp.x, pw10, pb1)));
      hm[j * 64 + HCOL(lane, j)] = f2bf(fmaxf(h1, 0.f));
    }
    f32x4 accp[4];
    mvl(hm, wlds, 0, bpe, ln, s0, s1, accp);       // posenc
    float vpe[4][4];
#pragma unroll
    for (int r = 0; r < 4; r++) {
      const int j = quad * 4 + r;
#pragma unroll
      for (int t = 0; t < 4; t++) {
        const unsigned w = kvw[r][t];
        float kf = __uint_as_float(w << 16);
        float vf = __uint_as_float(w & 0xFFFF0000u);
        float pe = accp[t][r];
        vpe[t][r] = vf + pe;
        hm[j * 64 + HCOL(t * 16 + ln, j)] = f2bf(qv[t] - kf + pe);
      }
    }
    f32x4 acch[4];
    mvl(hm, wlds, 1, ba1, ln, s0, s1, acch);       // hh @ at_w1 + b
#pragma unroll
    for (int t = 0; t < 4; t++)
#pragma unroll
      for (int r = 0; r < 4; r++) {
        const int j = quad * 4 + r;
        hm[j * 64 + HCOL(t * 16 + ln, j)] = f2bf(fmaxf(acch[t][r], 0.f));
      }
    f32x4 lg[4];
    mvl(hm, wlds, 2, ba2, ln, s0, s1, lg);         // logits
    const int pb = wid * 4 + pp;
#pragma unroll
    for (int t = 0; t < 4; t++) {                  // softmax (tiny logits)
      float e0 = __expf(lg[t][0] * 0.125f);
      float e1 = __expf(lg[t][1] * 0.125f);
      float e2 = __expf(lg[t][2] * 0.125f);
      float e3 = __expf(lg[t][3] * 0.125f);
      float ss = (e0 + e1) + (e2 + e3);
      float dt = fmaf(e3, vpe[t][3], fmaf(e2, vpe[t][2],
                 fmaf(e1, vpe[t][1], e0 * vpe[t][0])));
      ss += __shfl_xor(ss, 16); ss += __shfl_xor(ss, 32);
      dt += __shfl_xor(dt, 16); dt += __shfl_xor(dt, 32);
      float res = dt / ss;
      if (quad == 0) resm[pb * 64 + HCOL(t * 16 + ln, pb)] = f2bf(res);
    }
#pragma unroll
    for (int u = 0; u < 4; u++) cur[u] = nxt[u];
  }
  __syncthreads();
  {
    const int nt = wid;
    float ob = out_b[nt * 16 + ln];
    f32x4 acc = {ob, ob, ob, ob};
#pragma unroll
    for (int ks = 0; ks < 2; ks++) {
      bf16x8 a = *(const bf16x8*)(resm + ln * 64 +
                                  (((ks * 4 + quad + ln) & 7) << 3));
      acc = __builtin_amdgcn_mfma_f32_16x16x32_bf16(a, bo[ks], acc, 0, 0, 0);
    }
#pragma unroll
    for (int r = 0; r < 4; r++) {
      const int pt = blockIdx.x * 16 + quad * 4 + r;
      const int f = nt * 16 + ln;
      out[pt * 64 + f] = acc[r] + feat[pt * 64 + f];
    }
  }
}

// ============================ launcher ========================================
extern "C" void kernel_launch(void* const* d_in, const int* in_sizes, int n_in,
                              void* d_out, int out_size, void* d_ws, size_t ws_size,
                              hipStream_t stream)
{
  (void)in_sizes; (void)n_in; (void)out_size;
  const float* pos   = (const float*)d_in[0];
  const float* feat  = (const float*)d_in[1];
  const float* emb_w = (const float*)d_in[2];
  const float* emb_b = (const float*)d_in[3];
  const float* wq    = (const float*)d_in[4];
  const float* wk    = (const float*)d_in[5];
  const float* wv    = (const float*)d_in[6];
  const float* pe_w1 = (const float*)d_in[7];
  const float* pe_b1 = (const float*)d_in[8];
  const float* pe_w2 = (const float*)d_in[9];
  const float* pe_b2 = (const float*)d_in[10];
  const float* at_w1 = (const float*)d_in[11];
  const float* at_b1 = (const float*)d_in[12];
  const float* at_w2 = (const float*)d_in[13];
  const float* at_b2 = (const float*)d_in[14];
  const float* out_w = (const float*)d_in[15];
  const float* out_b = (const float*)d_in[16];
  float* ws = (float*)d_ws;

  // R20: runtime probe — wide (32-segment) KNN only if workspace fits part2.
  const bool wide = ws_size >= (size_t)WIDE_WORDS * 4u;
  if (wide) {
    mega1_t<32><<<2624, 256, 0, stream>>>(pos, feat, emb_w, emb_b, wq, wk, wv,
                                          pe_w2, at_w1, at_w2, out_w, ws);
    s3_merge_t<32><<<256, 64, 0, stream>>>(ws, (int*)ws + IDX_OFF);
  } else {
    mega1_t<16><<<1600, 256, 0, stream>>>(pos, feat, emb_w, emb_b, wq, wk, wv,
                                          pe_w2, at_w1, at_w2, out_w, ws);
    s3_merge_t<16><<<256, 64, 0, stream>>>(ws, (int*)ws + IDX_OFF);
  }
  s4_attn<<<NPTS / 16, 256, 0, stream>>>(ws, feat, pe_w1, pe_b1, pe_b2,
      at_b1, at_b2, out_b, (int*)ws + IDX_OFF, (float*)d_out);
}

// Round 11
// 210.179 us; speedup vs baseline: 2.1421x; 2.1421x over previous
//
#include <hip/hip_runtime.h>
#include <hip/hip_bf16.h>

#define BB 2
#define NN 8192
#define SPL 16
#define NPTS (BB*NN)

// ---- workspace layout (units: 4-byte words) ----
// Base layout (26.5 MB) unchanged from R4/R19. Wide mode (R20, proven -14%)
// adds part2 (16 MB) after the base region when ws_size permits: 32-segment
// KNN split -> 2048 A-blocks.
#define POS4_OFF 0u                     /* 65,536 w float4 (x,y,z,0) */
#define PART_OFF 65536u                 /* lists 0..255: [256][NPTS] 16MB */
#define IDX_OFF  4259840u               /* 262,144 w */
#define WT_OFF   4521984u               /* 4 mats x 4096 bf16 = 8,192 w */
#define QB_OFF   4530176u               /* 1,048,576 w */
#define KVB_OFF  5578752u               /* 1,048,576 w packed bf16 k|v */
#define PART2_OFF 6627328u              /* lists 256..511 (wide mode only) */
#define WIDE_WORDS (PART2_OFF + 4194304u)

typedef __attribute__((ext_vector_type(8))) short bf16x8;
typedef __attribute__((ext_vector_type(4))) float f32x4;

__device__ __forceinline__ unsigned umn(unsigned a, unsigned b) {
#if __has_builtin(__builtin_elementwise_min)
  return __builtin_elementwise_min(a, b);
#else
  return a < b ? a : b;
#endif
}
__device__ __forceinline__ unsigned umx(unsigned a, unsigned b) {
#if __has_builtin(__builtin_elementwise_max)
  return __builtin_elementwise_max(a, b);
#else
  return a < b ? b : a;
#endif
}

__device__ inline unsigned short f2bf(float x) {
  __hip_bfloat16 b = __float2bfloat16(x);
  return *(unsigned short*)&b;
}

// column-block rotate swizzle for conflict-free ds_read_b128 fragments
#define HCOL(c, j) ((((((c) >> 3) + (j)) & 7) << 3) | ((c) & 7))

// per-batch distance + OEMS-16 sort + merge into m[] (R12-proven math, exact)
#define SORTB(CC, JBASE)                                                    \
  do {                                                                      \
    unsigned b[16];                                                         \
    _Pragma("unroll")                                                       \
    for (int i = 0; i < 16; i++) {                                          \
      const float cx = CC[(3 * i) >> 2][(3 * i) & 3];                       \
      const float cy = CC[(3 * i + 1) >> 2][(3 * i + 1) & 3];               \
      const float cz = CC[(3 * i + 2) >> 2][(3 * i + 2) & 3];               \
      float dx = cx - qx, dy = cy - qy, dz = cz - qz;                       \
      float d2 = fmaf(dx, dx, fmaf(dy, dy, dz * dz));                       \
      b[i] = (__float_as_uint(d2) & 0xFFFFE000u) |                          \
             (jb + (unsigned)((JBASE) + i));                                \
    }                                                                       \
    _Pragma("unroll")                                                       \
    for (int cc2 = 0; cc2 < 63; cc2++) {                                    \
      const int x = OE[cc2][0], y = OE[cc2][1];                             \
      unsigned lo = umn(b[x], b[y]);                                        \
      unsigned hi = umx(b[x], b[y]);                                        \
      b[x] = hi; b[y] = lo;                                                 \
    }                                                                       \
    _Pragma("unroll")                                                       \
    for (int i = 0; i < 16; i++) m[i] = umn(m[i], b[i]);                    \
    _Pragma("unroll")                                                       \
    for (int d = 8; d; d >>= 1) {                                           \
      _Pragma("unroll")                                                     \
      for (int i = 0; i < 16; i++) {                                        \
        if ((i & d) == 0) {                                                 \
          const int l = i | d;                                              \
          unsigned lo = umn(m[i], m[l]);                                    \
          unsigned hi = umx(m[i], m[l]);                                    \
          m[i] = lo; m[l] = hi;                                             \
        }                                                                   \
      }                                                                     \
    }                                                                       \
  } while (0)

// ============================ MEGA1: KNN + qkv/pos4 + wt (role-split) =========
// R20-EXACT form (proven: 81 us, total 209.4). Role order: B [0,512) |
// C [512,576) | A [576, 576+64*NSEG). 24KB LDS, full-staged role B, natural
// VGPR=60.
// OCCUPANCY LADDER (counter-verified): 4 blk/CU=105us (R21, VGPR 72 crossed
// 64-cliff) | 6 blk/CU=81us (this form) | lb(256,8)=VGPR32+spill=317us (R22,
// FETCH 467MB). Do NOT add min-waves launch bounds; do NOT restructure role B.
template <int NSEG>
__global__ __launch_bounds__(256) void mega1_t(
    const float* __restrict__ pos, const float* __restrict__ feat,
    const float* __restrict__ emb_w, const float* __restrict__ emb_b,
    const float* __restrict__ wq, const float* __restrict__ wk,
    const float* __restrict__ wv,
    const float* __restrict__ pe_w2, const float* __restrict__ at_w1,
    const float* __restrict__ at_w2, const float* __restrict__ out_w,
    float* __restrict__ ws)
{
  __shared__ __align__(16) float smem[6144];   // 24 KB: wl[4096] | xl[2048]
  const int tid = threadIdx.x;
  const int bx = blockIdx.x;
  float* pos4 = ws + POS4_OFF;
  unsigned* part = (unsigned*)ws + PART_OFF;
  unsigned* part2 = (unsigned*)ws + PART2_OFF;
  float* qg = ws + QB_OFF;
  unsigned* kvp = (unsigned*)ws + KVB_OFF;
  constexpr int CANDN = NN / NSEG;

  if (bx >= 576) {
    // ---------------- role A: KNN (LDS-staged candidates, batch-16 OEMS) ----
    constexpr int OE[63][2] = {
      {0,1},{2,3},{4,5},{6,7},{8,9},{10,11},{12,13},{14,15},
      {0,2},{1,3},{4,6},{5,7},{8,10},{9,11},{12,14},{13,15},
      {1,2},{5,6},{9,10},{13,14},
      {0,4},{1,5},{2,6},{3,7},{8,12},{9,13},{10,14},{11,15},
      {2,4},{3,5},{10,12},{11,13},
      {1,2},{3,4},{5,6},{9,10},{11,12},{13,14},
      {0,8},{1,9},{2,10},{3,11},{4,12},{5,13},{6,14},{7,15},
      {4,8},{5,9},{6,10},{7,11},
      {2,4},{3,5},{6,8},{7,9},{10,12},{11,13},
      {1,2},{3,4},{5,6},{7,8},{9,10},{11,12},{13,14}
    };
    const int aIdx = bx - 576;
    const int g = (aIdx & 63) * 256 + tid;
    const int s = aIdx >> 6;                  // [0, NSEG)
    const int bu = __builtin_amdgcn_readfirstlane(g >> 13);
    const float qx = pos[g * 3 + 0], qy = pos[g * 3 + 1], qz = pos[g * 3 + 2];
    const unsigned jb = (unsigned)(s * CANDN);
    // stage this block's CANDN-candidate segment into LDS (coalesced f32x4)
    {
      const f32x4* segp = (const f32x4*)(pos + (bu * NN + s * CANDN) * 3);
      f32x4* cl4w = (f32x4*)smem;
      for (int i = tid; i < (CANDN * 3) / 4; i += 256) cl4w[i] = segp[i];
    }
    __syncthreads();
    const f32x4* cl4 = (const f32x4*)smem;
    unsigned m[16];
#pragma unroll
    for (int i = 0; i < 16; i++) m[i] = 0xFFFFFFFFu;
    f32x4 ca[12], cb[12];
#pragma unroll
    for (int i = 0; i < 12; i++) ca[i] = cl4[i];          // batch 0
    for (int j0 = 0; j0 < CANDN; j0 += 32) {
      const int b1 = ((j0 >> 4) + 1) * 12;                // batch j0+16
#pragma unroll
      for (int i = 0; i < 12; i++) cb[i] = cl4[b1 + i];
      SORTB(ca, j0);
      const int b2 = ((j0 + 32 < CANDN) ? ((j0 >> 4) + 2) : ((j0 >> 4) + 1)) * 12;
#pragma unroll
      for (int i = 0; i < 12; i++) ca[i] = cl4[b2 + i];   // batch j0+32 (clamped)
      SORTB(cb, j0 + 16);
    }
#pragma unroll
    for (int i = 0; i < 16; i++) {
      const unsigned L = (unsigned)(s * 16 + i);          // list index
      unsigned* dst = (L < 256u) ? (part + L * NPTS) : (part2 + (L - 256u) * NPTS);
      dst[(unsigned)g] = m[i];
    }
  } else if (bx < 512) {
    // ---------------- role B: pos4 + emb + qkv, 4-pass staging (R4-exact) ---
    float* wl = smem;            // 4096 floats (16 KB)
    float* xl = smem + 4096;     // 2048 floats (8 KB)
    const int vb = bx;
    const int col = tid & 63;
    const int rg = tid >> 6;
    const int row0 = vb * 32 + rg * 8;
    const int rowu = __builtin_amdgcn_readfirstlane(row0);
    if (tid < 32) {              // pos4 staging: 32 points/block
      const int p = vb * 32 + tid;
      float x = pos[p * 3 + 0], y = pos[p * 3 + 1], z = pos[p * 3 + 2];
      float4 v = {x, y, z, 0.f};
      ((float4*)pos4)[p] = v;
    }
    for (int i = tid; i < 4096; i += 256) wl[i] = emb_w[i];
    __syncthreads();
    {
      float acc[8];
      float bias = emb_b[col];
#pragma unroll
      for (int r = 0; r < 8; r++) acc[r] = bias;
      for (int c = 0; c < 64; c++) {
        float w = wl[c * 64 + col];
        const float* fp = feat + rowu * 64 + c;   // uniform -> scalar loads
#pragma unroll
        for (int r = 0; r < 8; r++) acc[r] = fmaf(fp[r * 64], w, acc[r]);
      }
#pragma unroll
      for (int r = 0; r < 8; r++) xl[(rg * 8 + r) * 64 + col] = acc[r];
    }
    __syncthreads();
    for (int i = tid; i < 4096; i += 256) wl[i] = wq[i];
    __syncthreads();
    {
      float aq[8];
#pragma unroll
      for (int r = 0; r < 8; r++) aq[r] = 0.f;
      for (int c = 0; c < 64; c++) {
        float w = wl[c * 64 + col];
#pragma unroll
        for (int r = 0; r < 8; r++)
          aq[r] = fmaf(xl[(rg * 8 + r) * 64 + c], w, aq[r]);
      }
#pragma unroll
      for (int r = 0; r < 8; r++) qg[(row0 + r) * 64 + col] = aq[r];
    }
    __syncthreads();
    for (int i = tid; i < 4096; i += 256) wl[i] = wk[i];
    __syncthreads();
    float ak[8];
    {
#pragma unroll
      for (int r = 0; r < 8; r++) ak[r] = 0.f;
      for (int c = 0; c < 64; c++) {
        float w = wl[c * 64 + col];
#pragma unroll
        for (int r = 0; r < 8; r++)
          ak[r] = fmaf(xl[(rg * 8 + r) * 64 + c], w, ak[r]);
      }
    }
    __syncthreads();
    for (int i = tid; i < 4096; i += 256) wl[i] = wv[i];
    __syncthreads();
    {
      float av[8];
#pragma unroll
      for (int r = 0; r < 8; r++) av[r] = 0.f;
      for (int c = 0; c < 64; c++) {
        float w = wl[c * 64 + col];
#pragma unroll
        for (int r = 0; r < 8; r++)
          av[r] = fmaf(xl[(rg * 8 + r) * 64 + c], w, av[r]);
      }
#pragma unroll
      for (int r = 0; r < 8; r++)
        kvp[(row0 + r) * 64 + col] =
            ((unsigned)f2bf(av[r]) << 16) | (unsigned)f2bf(ak[r]);
    }
  } else {
    // ---------------- role C: wt bf16-T staging ----------------
    const int t = (bx - 512) * 256 + tid;    // wt[m*4096+f*64+c]=W_m[c*64+f]
    const float* s;
    switch (t >> 12) {
      case 0: s = pe_w2; break;
      case 1: s = at_w1; break;
      case 2: s = at_w2; break;
      default: s = out_w; break;
    }
    const int idx = t & 4095, f = idx >> 6, c = idx & 63;
    ((unsigned short*)(ws + WT_OFF))[t] = f2bf(s[c * 64 + f]);
  }
}

// ============================ S3: merge NSEG sorted 16-lists (coalesced) ======
// R16/R18: keep standalone (fusion into s4 regressed twice).
// R22-kept piece: 256 blocks x 64 threads (was 64x256) — same per-thread code
// and coalescing (64 consecutive g per wave), spreads over all 256 CUs.
template <int NSEG>
__global__ __launch_bounds__(64) void s3_merge_t(const float* __restrict__ ws_ro,
                                                 int* __restrict__ knn_idx)
{
  const unsigned* part = (const unsigned*)ws_ro + PART_OFF;
  const unsigned* part2 = (const unsigned*)ws_ro + PART2_OFF;
  const int g = blockIdx.x * 64 + threadIdx.x;
  unsigned run[16];
#pragma unroll
  for (int i = 0; i < 16; i++) run[i] = part[i * NPTS + g];
#pragma unroll
  for (int l = 1; l < NSEG; l++) {
#pragma unroll
    for (int i = 0; i < 16; i++) {
      const int L = l * 16 + 15 - i;
      const unsigned v = (L < 256) ? part[L * NPTS + g]
                                   : part2[(L - 256) * NPTS + g];
      run[i] = umn(run[i], v);
    }
#pragma unroll
    for (int d = 8; d; d >>= 1) {
#pragma unroll
      for (int i = 0; i < 16; i++) {
        if ((i & d) == 0) {
          const int l2 = i | d;
          unsigned lo = umn(run[i], run[l2]);
          unsigned hi = umx(run[i], run[l2]);
          run[i] = lo; run[l2] = hi;
        }
      }
    }
  }
  const int base = (g >> 13) * NN;
  int outv[16];
#pragma unroll
  for (int i = 0; i < 16; i++) outv[i] = base + (int)(run[i] & 0x1FFFu);
  int4* o = (int4*)(knn_idx + g * 16);
  o[0] = make_int4(outv[0], outv[1], outv[2], outv[3]);
  o[1] = make_int4(outv[4], outv[5], outv[6], outv[7]);
  o[2] = make_int4(outv[8], outv[9], outv[10], outv[11]);
  o[3] = make_int4(outv[12], outv[13], outv[14], outv[15]);
}

// ============================ S4: MFMA fused posenc/attn/softmax/out ==========
// R19-proven EXACT (won -12 us): mv weights in 12KB swizzled LDS, not 96 VGPRs.
__device__ inline void mvl(const unsigned short* hm, const unsigned short* wl,
                           int mat, const float bias[4], int ln, int s0, int s1,
                           f32x4 acc[4])
{
  bf16x8 a0 = *(const bf16x8*)(hm + ln * 64 + s0);
  bf16x8 a1 = *(const bf16x8*)(hm + ln * 64 + s1);
#pragma unroll
  for (int t = 0; t < 4; t++) {
    const unsigned short* wr = wl + mat * 4096 + (t * 16 + ln) * 64;
    bf16x8 B0 = *(const bf16x8*)(wr + s0);
    bf16x8 B1 = *(const bf16x8*)(wr + s1);
    f32x4 a = {bias[t], bias[t], bias[t], bias[t]};
    a = __builtin_amdgcn_mfma_f32_16x16x32_bf16(a0, B0, a, 0, 0, 0);
    a = __builtin_amdgcn_mfma_f32_16x16x32_bf16(a1, B1, a, 0, 0, 0);
    acc[t] = a;
  }
}

__global__ __launch_bounds__(256, 2) void s4_attn(
    const float* __restrict__ ws_ro, const float* __restrict__ feat,
    const float* __restrict__ pe_w1, const float* __restrict__ pe_b1,
    const float* __restrict__ pe_b2, const float* __restrict__ at_b1,
    const float* __restrict__ at_b2, const float* __restrict__ out_b,
    const int* __restrict__ knn, float* __restrict__ out)
{
  __shared__ unsigned short hma[4][1024];       // per-wave 16x64 bf16 h (8 KB)
  __shared__ unsigned short resm[1024];         // 16 points x 64 bf16   (2 KB)
  __shared__ __align__(16) unsigned short wlds[12288];  // 3 mats swizzled
  const float* pos4 = ws_ro + POS4_OFF;
  const float* qg = ws_ro + QB_OFF;
  const unsigned* kvp = (const unsigned*)ws_ro + KVB_OFF;
  const unsigned short* wt = (const unsigned short*)(ws_ro + WT_OFF);

  const int tid = threadIdx.x;
  const int wid = tid >> 6, lane = tid & 63;
  const int ln = lane & 15, quad = lane >> 4;
  unsigned short* hm = hma[wid];
  const int s0 = ((quad + ln) & 7) << 3;
  const int s1 = ((4 + quad + ln) & 7) << 3;

  // ---- stage mv weight mats 0-2 into LDS with HCOL block swizzle ----
  {
    const bf16x8* src = (const bf16x8*)wt;      // 1536 blocks of 16 B (3 mats)
    bf16x8* dst = (bf16x8*)wlds;
    for (int i = tid; i < 1536; i += 256) {
      const int blk = i & 511, row = blk >> 3, cb = blk & 7;
      dst[(i & ~511) + (row << 3) + ((cb + row) & 7)] = src[i];
    }
  }

  bf16x8 bo[2];
#pragma unroll
  for (int ks = 0; ks < 2; ks++)
    bo[ks] = *(const bf16x8*)(wt + 3 * 4096 + (wid * 16 + ln) * 64 +
                              ks * 32 + quad * 8);

  float pw10 = pe_w1[lane], pw11 = pe_w1[64 + lane], pw12 = pe_w1[128 + lane];
  float pb1 = pe_b1[lane];
  float bpe[4], ba1[4], ba2[4];
#pragma unroll
  for (int t = 0; t < 4; t++) {
    bpe[t] = pe_b2[t * 16 + ln];
    ba1[t] = at_b1[t * 16 + ln];
    ba2[t] = at_b2[t * 16 + ln];
  }
  const float4* pp4 = (const float4*)pos4;

  const int p0 = blockIdx.x * 16 + wid * 4;
  const int ps0 = __builtin_amdgcn_readfirstlane(p0);
  int4 cur[4];
  {
    const int4* ip4 = (const int4*)(knn + ps0 * 16);
#pragma unroll
    for (int u = 0; u < 4; u++) cur[u] = ip4[u];
  }
  __syncthreads();   // wlds ready for all waves

#pragma unroll 1
  for (int pp = 0; pp < 4; pp++) {
    asm volatile("" ::: "memory");   // keep B-frags in LDS, not hoisted regs
    const int p = p0 + pp;
    const int ps = __builtin_amdgcn_readfirstlane(p);
    int jj[16];
#pragma unroll
    for (int u = 0; u < 4; u++) {
      jj[u*4+0] = cur[u].x; jj[u*4+1] = cur[u].y;
      jj[u*4+2] = cur[u].z; jj[u*4+3] = cur[u].w;
    }
    int4 nxt[4];
    {
      const int pn = (pp < 3) ? (ps + 1) : ps;
      const int4* np4 = (const int4*)(knn + pn * 16);
#pragma unroll
      for (int u = 0; u < 4; u++) nxt[u] = np4[u];
    }
    unsigned kvw[4][4];                    // early gathers (hide under mv1)
#pragma unroll
    for (int r = 0; r < 4; r++) {
      const unsigned* kp = kvp + jj[quad * 4 + r] * 64 + ln;
#pragma unroll
      for (int t = 0; t < 4; t++) kvw[r][t] = kp[t * 16];
    }
    float qv[4];
#pragma unroll
    for (int t = 0; t < 4; t++) qv[t] = qg[p * 64 + t * 16 + ln];

    const float4 mp = pp4[ps];
#pragma unroll
    for (int j = 0; j < 16; j++) {
      const float4 np = pp4[jj[j]];
      float h1 = fmaf(np.z - mp.z, pw12,
                 fmaf(np.y - mp.y, pw11,
                 fmaf(np.x - mp.x, pw10, pb1)));
      hm[j * 64 + HCOL(lane, j)] = f2bf(fmaxf(h1, 0.f));
    }
    f32x4 accp[4];
    mvl(hm, wlds, 0, bpe, ln, s0, s1, accp);       // posenc
    float vpe[4][4];
#pragma unroll
    for (int r = 0; r < 4; r++) {
      const int j = quad * 4 + r;
#pragma unroll
      for (int t = 0; t < 4; t++) {
        const unsigned w = kvw[r][t];
        float kf = __uint_as_float(w << 16);
        float vf = __uint_as_float(w & 0xFFFF0000u);
        float pe = accp[t][r];
        vpe[t][r] = vf + pe;
        hm[j * 64 + HCOL(t * 16 + ln, j)] = f2bf(qv[t] - kf + pe);
      }
    }
    f32x4 acch[4];
    mvl(hm, wlds, 1, ba1, ln, s0, s1, acch);       // hh @ at_w1 + b
#pragma unroll
    for (int t = 0; t < 4; t++)
#pragma unroll
      for (int r = 0; r < 4; r++) {
        const int j = quad * 4 + r;
        hm[j * 64 + HCOL(t * 16 + ln, j)] = f2bf(fmaxf(acch[t][r], 0.f));
      }
    f32x4 lg[4];
    mvl(hm, wlds, 2, ba2, ln, s0, s1, lg);         // logits
    const int pb = wid * 4 + pp;
#pragma unroll
    for (int t = 0; t < 4; t++) {                  // softmax (tiny logits)
      float e0 = __expf(lg[t][0] * 0.125f);
      float e1 = __expf(lg[t][1] * 0.125f);
      float e2 = __expf(lg[t][2] * 0.125f);
      float e3 = __expf(lg[t][3] * 0.125f);
      float ss = (e0 + e1) + (e2 + e3);
      float dt = fmaf(e3, vpe[t][3], fmaf(e2, vpe[t][2],
                 fmaf(e1, vpe[t][1], e0 * vpe[t][0])));
      ss += __shfl_xor(ss, 16); ss += __shfl_xor(ss, 32);
      dt += __shfl_xor(dt, 16); dt += __shfl_xor(dt, 32);
      float res = dt / ss;
      if (quad == 0) resm[pb * 64 + HCOL(t * 16 + ln, pb)] = f2bf(res);
    }
#pragma unroll
    for (int u = 0; u < 4; u++) cur[u] = nxt[u];
  }
  __syncthreads();
  {
    const int nt = wid;
    float ob = out_b[nt * 16 + ln];
    f32x4 acc = {ob, ob, ob, ob};
#pragma unroll
    for (int ks = 0; ks < 2; ks++) {
      bf16x8 a = *(const bf16x8*)(resm + ln * 64 +
                                  (((ks * 4 + quad + ln) & 7) << 3));
      acc = __builtin_amdgcn_mfma_f32_16x16x32_bf16(a, bo[ks], acc, 0, 0, 0);
    }
#pragma unroll
    for (int r = 0; r < 4; r++) {
      const int pt = blockIdx.x * 16 + quad * 4 + r;
      const int f = nt * 16 + ln;
      out[pt * 64 + f] = acc[r] + feat[pt * 64 + f];
    }
  }
}

// ============================ launcher ========================================
extern "C" void kernel_launch(void* const* d_in, const int* in_sizes, int n_in,
                              void* d_out, int out_size, void* d_ws, size_t ws_size,
                              hipStream_t stream)
{
  (void)in_sizes; (void)n_in; (void)out_size;
  const float* pos   = (const float*)d_in[0];
  const float* feat  = (const float*)d_in[1];
  const float* emb_w = (const float*)d_in[2];
  const float* emb_b = (const float*)d_in[3];
  const float* wq    = (const float*)d_in[4];
  const float* wk    = (const float*)d_in[5];
  const float* wv    = (const float*)d_in[6];
  const float* pe_w1 = (const float*)d_in[7];
  const float* pe_b1 = (const float*)d_in[8];
  const float* pe_w2 = (const float*)d_in[9];
  const float* pe_b2 = (const float*)d_in[10];
  const float* at_w1 = (const float*)d_in[11];
  const float* at_b1 = (const float*)d_in[12];
  const float* at_w2 = (const float*)d_in[13];
  const float* at_b2 = (const float*)d_in[14];
  const float* out_w = (const float*)d_in[15];
  const float* out_b = (const float*)d_in[16];
  float* ws = (float*)d_ws;

  // R20: runtime probe — wide (32-segment) KNN only if workspace fits part2.
  const bool wide = ws_size >= (size_t)WIDE_WORDS * 4u;
  if (wide) {
    mega1_t<32><<<2624, 256, 0, stream>>>(pos, feat, emb_w, emb_b, wq, wk, wv,
                                          pe_w2, at_w1, at_w2, out_w, ws);
    s3_merge_t<32><<<256, 64, 0, stream>>>(ws, (int*)ws + IDX_OFF);
  } else {
    mega1_t<16><<<1600, 256, 0, stream>>>(pos, feat, emb_w, emb_b, wq, wk, wv,
                                          pe_w2, at_w1, at_w2, out_w, ws);
    s3_merge_t<16><<<256, 64, 0, stream>>>(ws, (int*)ws + IDX_OFF);
  }
  s4_attn<<<NPTS / 16, 256, 0, stream>>>(ws, feat, pe_w1, pe_b1, pe_b2,
      at_b1, at_b2, out_b, (int*)ws + IDX_OFF, (float*)d_out);
}

// Round 12
// 208.687 us; speedup vs baseline: 2.1574x; 1.0072x over previous
//
#include <hip/hip_runtime.h>
#include <hip/hip_bf16.h>

#define BB 2
#define NN 8192
#define SPL 16
#define NPTS (BB*NN)

// ---- workspace layout (units: 4-byte words) ----
#define POS4_OFF 0u                     /* 65,536 w float4 (x,y,z,0) */
#define PART_OFF 65536u                 /* lists 0..255: [256][NPTS] 16MB */
#define IDX_OFF  4259840u               /* 262,144 w */
#define WT_OFF   4521984u               /* 4 mats x 4096 bf16 = 8,192 w */
#define QB_OFF   4530176u               /* 1,048,576 w */
#define KVB_OFF  5578752u               /* 1,048,576 w packed bf16 k|v */
#define PART2_OFF 6627328u              /* lists 256..511 (wide mode only) */
#define WIDE_WORDS (PART2_OFF + 4194304u)

typedef __attribute__((ext_vector_type(8))) short bf16x8;
typedef __attribute__((ext_vector_type(4))) float f32x4;

__device__ __forceinline__ unsigned umn(unsigned a, unsigned b) {
#if __has_builtin(__builtin_elementwise_min)
  return __builtin_elementwise_min(a, b);
#else
  return a < b ? a : b;
#endif
}
__device__ __forceinline__ unsigned umx(unsigned a, unsigned b) {
#if __has_builtin(__builtin_elementwise_max)
  return __builtin_elementwise_max(a, b);
#else
  return a < b ? b : a;
#endif
}

__device__ inline unsigned short f2bf(float x) {
  __hip_bfloat16 b = __float2bfloat16(x);
  return *(unsigned short*)&b;
}

// column-block rotate swizzle for conflict-free ds_read_b128 fragments
#define HCOL(c, j) ((((((c) >> 3) + (j)) & 7) << 3) | ((c) & 7))

// per-batch distance + OEMS-16 sort + merge into m[] (R12-proven math, exact)
#define SORTB(CC, JBASE)                                                    \
  do {                                                                      \
    unsigned b[16];                                                         \
    _Pragma("unroll")                                                       \
    for (int i = 0; i < 16; i++) {                                          \
      const float cx = CC[(3 * i) >> 2][(3 * i) & 3];                       \
      const float cy = CC[(3 * i + 1) >> 2][(3 * i + 1) & 3];               \
      const float cz = CC[(3 * i + 2) >> 2][(3 * i + 2) & 3];               \
      float dx = cx - qx, dy = cy - qy, dz = cz - qz;                       \
      float d2 = fmaf(dx, dx, fmaf(dy, dy, dz * dz));                       \
      b[i] = (__float_as_uint(d2) & 0xFFFFE000u) |                          \
             (jb + (unsigned)((JBASE) + i));                                \
    }                                                                       \
    _Pragma("unroll")                                                       \
    for (int cc2 = 0; cc2 < 63; cc2++) {                                    \
      const int x = OE[cc2][0], y = OE[cc2][1];                             \
      unsigned lo = umn(b[x], b[y]);                                        \
      unsigned hi = umx(b[x], b[y]);                                        \
      b[x] = hi; b[y] = lo;                                                 \
    }                                                                       \
    _Pragma("unroll")                                                       \
    for (int i = 0; i < 16; i++) m[i] = umn(m[i], b[i]);                    \
    _Pragma("unroll")                                                       \
    for (int d = 8; d; d >>= 1) {                                           \
      _Pragma("unroll")                                                     \
      for (int i = 0; i < 16; i++) {                                        \
        if ((i & d) == 0) {                                                 \
          const int l = i | d;                                              \
          unsigned lo = umn(m[i], m[l]);                                    \
          unsigned hi = umx(m[i], m[l]);                                    \
          m[i] = lo; m[l] = hi;                                             \
        }                                                                   \
      }                                                                     \
    }                                                                       \
  } while (0)

// ============================ MEGA1: KNN + qkv/pos4 + wt (role-split) =========
// R20-EXACT form (proven: 82 us, total ~210). Role order: B [0,512) |
// C [512,576) | A [576, 576+64*NSEG). 24KB LDS, full-staged role B, natural
// VGPR=60.
// OCCUPANCY LADDER (counter-verified): 4 blk/CU=105us (R21, VGPR 72 crossed
// 64-cliff) | 6 blk/CU=82us (this form) | lb(256,8)=VGPR32+spill=317us (R22,
// FETCH 467MB). Do NOT add min-waves launch bounds; do NOT restructure role B.
template <int NSEG>
__global__ __launch_bounds__(256) void mega1_t(
    const float* __restrict__ pos, const float* __restrict__ feat,
    const float* __restrict__ emb_w, const float* __restrict__ emb_b,
    const float* __restrict__ wq, const float* __restrict__ wk,
    const float* __restrict__ wv,
    const float* __restrict__ pe_w2, const float* __restrict__ at_w1,
    const float* __restrict__ at_w2, const float* __restrict__ out_w,
    float* __restrict__ ws)
{
  __shared__ __align__(16) float smem[6144];   // 24 KB: wl[4096] | xl[2048]
  const int tid = threadIdx.x;
  const int bx = blockIdx.x;
  float* pos4 = ws + POS4_OFF;
  unsigned* part = (unsigned*)ws + PART_OFF;
  unsigned* part2 = (unsigned*)ws + PART2_OFF;
  float* qg = ws + QB_OFF;
  unsigned* kvp = (unsigned*)ws + KVB_OFF;
  constexpr int CANDN = NN / NSEG;

  if (bx >= 576) {
    // ---------------- role A: KNN (LDS-staged candidates, batch-16 OEMS) ----
    constexpr int OE[63][2] = {
      {0,1},{2,3},{4,5},{6,7},{8,9},{10,11},{12,13},{14,15},
      {0,2},{1,3},{4,6},{5,7},{8,10},{9,11},{12,14},{13,15},
      {1,2},{5,6},{9,10},{13,14},
      {0,4},{1,5},{2,6},{3,7},{8,12},{9,13},{10,14},{11,15},
      {2,4},{3,5},{10,12},{11,13},
      {1,2},{3,4},{5,6},{9,10},{11,12},{13,14},
      {0,8},{1,9},{2,10},{3,11},{4,12},{5,13},{6,14},{7,15},
      {4,8},{5,9},{6,10},{7,11},
      {2,4},{3,5},{6,8},{7,9},{10,12},{11,13},
      {1,2},{3,4},{5,6},{7,8},{9,10},{11,12},{13,14}
    };
    const int aIdx = bx - 576;
    const int g = (aIdx & 63) * 256 + tid;
    const int s = aIdx >> 6;                  // [0, NSEG)
    const int bu = __builtin_amdgcn_readfirstlane(g >> 13);
    const float qx = pos[g * 3 + 0], qy = pos[g * 3 + 1], qz = pos[g * 3 + 2];
    const unsigned jb = (unsigned)(s * CANDN);
    // stage this block's CANDN-candidate segment into LDS (coalesced f32x4)
    {
      const f32x4* segp = (const f32x4*)(pos + (bu * NN + s * CANDN) * 3);
      f32x4* cl4w = (f32x4*)smem;
      for (int i = tid; i < (CANDN * 3) / 4; i += 256) cl4w[i] = segp[i];
    }
    __syncthreads();
    const f32x4* cl4 = (const f32x4*)smem;
    unsigned m[16];
#pragma unroll
    for (int i = 0; i < 16; i++) m[i] = 0xFFFFFFFFu;
    f32x4 ca[12], cb[12];
#pragma unroll
    for (int i = 0; i < 12; i++) ca[i] = cl4[i];          // batch 0
    for (int j0 = 0; j0 < CANDN; j0 += 32) {
      const int b1 = ((j0 >> 4) + 1) * 12;                // batch j0+16
#pragma unroll
      for (int i = 0; i < 12; i++) cb[i] = cl4[b1 + i];
      SORTB(ca, j0);
      const int b2 = ((j0 + 32 < CANDN) ? ((j0 >> 4) + 2) : ((j0 >> 4) + 1)) * 12;
#pragma unroll
      for (int i = 0; i < 12; i++) ca[i] = cl4[b2 + i];   // batch j0+32 (clamped)
      SORTB(cb, j0 + 16);
    }
#pragma unroll
    for (int i = 0; i < 16; i++) {
      const unsigned L = (unsigned)(s * 16 + i);          // list index
      unsigned* dst = (L < 256u) ? (part + L * NPTS) : (part2 + (L - 256u) * NPTS);
      dst[(unsigned)g] = m[i];
    }
  } else if (bx < 512) {
    // ---------------- role B: pos4 + emb + qkv, 4-pass staging (R4-exact) ---
    float* wl = smem;            // 4096 floats (16 KB)
    float* xl = smem + 4096;     // 2048 floats (8 KB)
    const int vb = bx;
    const int col = tid & 63;
    const int rg = tid >> 6;
    const int row0 = vb * 32 + rg * 8;
    const int rowu = __builtin_amdgcn_readfirstlane(row0);
    if (tid < 32) {              // pos4 staging: 32 points/block
      const int p = vb * 32 + tid;
      float x = pos[p * 3 + 0], y = pos[p * 3 + 1], z = pos[p * 3 + 2];
      float4 v = {x, y, z, 0.f};
      ((float4*)pos4)[p] = v;
    }
    for (int i = tid; i < 4096; i += 256) wl[i] = emb_w[i];
    __syncthreads();
    {
      float acc[8];
      float bias = emb_b[col];
#pragma unroll
      for (int r = 0; r < 8; r++) acc[r] = bias;
      for (int c = 0; c < 64; c++) {
        float w = wl[c * 64 + col];
        const float* fp = feat + rowu * 64 + c;   // uniform -> scalar loads
#pragma unroll
        for (int r = 0; r < 8; r++) acc[r] = fmaf(fp[r * 64], w, acc[r]);
      }
#pragma unroll
      for (int r = 0; r < 8; r++) xl[(rg * 8 + r) * 64 + col] = acc[r];
    }
    __syncthreads();
    for (int i = tid; i < 4096; i += 256) wl[i] = wq[i];
    __syncthreads();
    {
      float aq[8];
#pragma unroll
      for (int r = 0; r < 8; r++) aq[r] = 0.f;
      for (int c = 0; c < 64; c++) {
        float w = wl[c * 64 + col];
#pragma unroll
        for (int r = 0; r < 8; r++)
          aq[r] = fmaf(xl[(rg * 8 + r) * 64 + c], w, aq[r]);
      }
#pragma unroll
      for (int r = 0; r < 8; r++) qg[(row0 + r) * 64 + col] = aq[r];
    }
    __syncthreads();
    for (int i = tid; i < 4096; i += 256) wl[i] = wk[i];
    __syncthreads();
    float ak[8];
    {
#pragma unroll
      for (int r = 0; r < 8; r++) ak[r] = 0.f;
      for (int c = 0; c < 64; c++) {
        float w = wl[c * 64 + col];
#pragma unroll
        for (int r = 0; r < 8; r++)
          ak[r] = fmaf(xl[(rg * 8 + r) * 64 + c], w, ak[r]);
      }
    }
    __syncthreads();
    for (int i = tid; i < 4096; i += 256) wl[i] = wv[i];
    __syncthreads();
    {
      float av[8];
#pragma unroll
      for (int r = 0; r < 8; r++) av[r] = 0.f;
      for (int c = 0; c < 64; c++) {
        float w = wl[c * 64 + col];
#pragma unroll
        for (int r = 0; r < 8; r++)
          av[r] = fmaf(xl[(rg * 8 + r) * 64 + c], w, av[r]);
      }
#pragma unroll
      for (int r = 0; r < 8; r++)
        kvp[(row0 + r) * 64 + col] =
            ((unsigned)f2bf(av[r]) << 16) | (unsigned)f2bf(ak[r]);
    }
  } else {
    // ---------------- role C: wt bf16-T staging ----------------
    const int t = (bx - 512) * 256 + tid;    // wt[m*4096+f*64+c]=W_m[c*64+f]
    const float* s;
    switch (t >> 12) {
      case 0: s = pe_w2; break;
      case 1: s = at_w1; break;
      case 2: s = at_w2; break;
      default: s = out_w; break;
    }
    const int idx = t & 4095, f = idx >> 6, c = idx & 63;
    ((unsigned short*)(ws + WT_OFF))[t] = f2bf(s[c * 64 + f]);
  }
}

// ============================ S3: merge NSEG sorted 16-lists (coalesced) ======
// R16/R18: keep standalone (fusion into s4 regressed twice).
// 256 blocks x 64 threads (R23): spreads over all 256 CUs, same coalescing.
template <int NSEG>
__global__ __launch_bounds__(64) void s3_merge_t(const float* __restrict__ ws_ro,
                                                 int* __restrict__ knn_idx)
{
  const unsigned* part = (const unsigned*)ws_ro + PART_OFF;
  const unsigned* part2 = (const unsigned*)ws_ro + PART2_OFF;
  const int g = blockIdx.x * 64 + threadIdx.x;
  unsigned run[16];
#pragma unroll
  for (int i = 0; i < 16; i++) run[i] = part[i * NPTS + g];
#pragma unroll
  for (int l = 1; l < NSEG; l++) {
#pragma unroll
    for (int i = 0; i < 16; i++) {
      const int L = l * 16 + 15 - i;
      const unsigned v = (L < 256) ? part[L * NPTS + g]
                                   : part2[(L - 256) * NPTS + g];
      run[i] = umn(run[i], v);
    }
#pragma unroll
    for (int d = 8; d; d >>= 1) {
#pragma unroll
      for (int i = 0; i < 16; i++) {
        if ((i & d) == 0) {
          const int l2 = i | d;
          unsigned lo = umn(run[i], run[l2]);
          unsigned hi = umx(run[i], run[l2]);
          run[i] = lo; run[l2] = hi;
        }
      }
    }
  }
  const int base = (g >> 13) * NN;
  int outv[16];
#pragma unroll
  for (int i = 0; i < 16; i++) outv[i] = base + (int)(run[i] & 0x1FFFu);
  int4* o = (int4*)(knn_idx + g * 16);
  o[0] = make_int4(outv[0], outv[1], outv[2], outv[3]);
  o[1] = make_int4(outv[4], outv[5], outv[6], outv[7]);
  o[2] = make_int4(outv[8], outv[9], outv[10], outv[11]);
  o[3] = make_int4(outv[12], outv[13], outv[14], outv[15]);
}

// ============================ S4: MFMA fused posenc/attn/softmax/out ==========
// R19-proven structure (mv weights in swizzled LDS). R24 change: the posenc
// np gather pp4[jj[j]] is WAVE-UNIFORM (jj loaded from a uniform knn address)
// — previously 64 redundant per-lane VMEM gathers per j (16 KB/wave/pp of L2
// traffic + VMEM stall + 16 float4 of VGPR pressure). readfirstlane(jj[j])
// makes the pointer provably uniform -> s_load_dwordx4 into SGPRs; the h1
// fma chain reads <=1 SGPR per VALU op (dx/dy/dz via v_sub from one v_mov'd
// mp). Theory: s4 is latency-bound (R3: real VALUBusy ~13%, MfmaUtil 2.5%).
__device__ inline void mvl(const unsigned short* hm, const unsigned short* wl,
                           int mat, const float bias[4], int ln, int s0, int s1,
                           f32x4 acc[4])
{
  bf16x8 a0 = *(const bf16x8*)(hm + ln * 64 + s0);
  bf16x8 a1 = *(const bf16x8*)(hm + ln * 64 + s1);
#pragma unroll
  for (int t = 0; t < 4; t++) {
    const unsigned short* wr = wl + mat * 4096 + (t * 16 + ln) * 64;
    bf16x8 B0 = *(const bf16x8*)(wr + s0);
    bf16x8 B1 = *(const bf16x8*)(wr + s1);
    f32x4 a = {bias[t], bias[t], bias[t], bias[t]};
    a = __builtin_amdgcn_mfma_f32_16x16x32_bf16(a0, B0, a, 0, 0, 0);
    a = __builtin_amdgcn_mfma_f32_16x16x32_bf16(a1, B1, a, 0, 0, 0);
    acc[t] = a;
  }
}

__global__ __launch_bounds__(256, 2) void s4_attn(
    const float* __restrict__ ws_ro, const float* __restrict__ feat,
    const float* __restrict__ pe_w1, const float* __restrict__ pe_b1,
    const float* __restrict__ pe_b2, const float* __restrict__ at_b1,
    const float* __restrict__ at_b2, const float* __restrict__ out_b,
    const int* __restrict__ knn, float* __restrict__ out)
{
  __shared__ unsigned short hma[4][1024];       // per-wave 16x64 bf16 h (8 KB)
  __shared__ unsigned short resm[1024];         // 16 points x 64 bf16   (2 KB)
  __shared__ __align__(16) unsigned short wlds[12288];  // 3 mats swizzled
  const float* pos4 = ws_ro + POS4_OFF;
  const float* qg = ws_ro + QB_OFF;
  const unsigned* kvp = (const unsigned*)ws_ro + KVB_OFF;
  const unsigned short* wt = (const unsigned short*)(ws_ro + WT_OFF);

  const int tid = threadIdx.x;
  const int wid = tid >> 6, lane = tid & 63;
  const int ln = lane & 15, quad = lane >> 4;
  unsigned short* hm = hma[wid];
  const int s0 = ((quad + ln) & 7) << 3;
  const int s1 = ((4 + quad + ln) & 7) << 3;

  // ---- stage mv weight mats 0-2 into LDS with HCOL block swizzle ----
  {
    const bf16x8* src = (const bf16x8*)wt;      // 1536 blocks of 16 B (3 mats)
    bf16x8* dst = (bf16x8*)wlds;
    for (int i = tid; i < 1536; i += 256) {
      const int blk = i & 511, row = blk >> 3, cb = blk & 7;
      dst[(i & ~511) + (row << 3) + ((cb + row) & 7)] = src[i];
    }
  }

  bf16x8 bo[2];
#pragma unroll
  for (int ks = 0; ks < 2; ks++)
    bo[ks] = *(const bf16x8*)(wt + 3 * 4096 + (wid * 16 + ln) * 64 +
                              ks * 32 + quad * 8);

  float pw10 = pe_w1[lane], pw11 = pe_w1[64 + lane], pw12 = pe_w1[128 + lane];
  float pb1 = pe_b1[lane];
  float bpe[4], ba1[4], ba2[4];
#pragma unroll
  for (int t = 0; t < 4; t++) {
    bpe[t] = pe_b2[t * 16 + ln];
    ba1[t] = at_b1[t * 16 + ln];
    ba2[t] = at_b2[t * 16 + ln];
  }
  const float4* pp4 = (const float4*)pos4;

  const int p0 = blockIdx.x * 16 + wid * 4;
  const int ps0 = __builtin_amdgcn_readfirstlane(p0);
  int4 cur[4];
  {
    const int4* ip4 = (const int4*)(knn + ps0 * 16);
#pragma unroll
    for (int u = 0; u < 4; u++) cur[u] = ip4[u];
  }
  __syncthreads();   // wlds ready for all waves

#pragma unroll 1
  for (int pp = 0; pp < 4; pp++) {
    asm volatile("" ::: "memory");   // keep B-frags in LDS, not hoisted regs
    const int p = p0 + pp;
    const int ps = __builtin_amdgcn_readfirstlane(p);
    int jj[16];
#pragma unroll
    for (int u = 0; u < 4; u++) {
      jj[u*4+0] = cur[u].x; jj[u*4+1] = cur[u].y;
      jj[u*4+2] = cur[u].z; jj[u*4+3] = cur[u].w;
    }
    int4 nxt[4];
    {
      const int pn = (pp < 3) ? (ps + 1) : ps;
      const int4* np4 = (const int4*)(knn + pn * 16);
#pragma unroll
      for (int u = 0; u < 4; u++) nxt[u] = np4[u];
    }
    unsigned kvw[4][4];                    // early gathers (hide under mv1)
#pragma unroll
    for (int r = 0; r < 4; r++) {
      const unsigned* kp = kvp + jj[quad * 4 + r] * 64 + ln;
#pragma unroll
      for (int t = 0; t < 4; t++) kvw[r][t] = kp[t * 16];
    }
    float qv[4];
#pragma unroll
    for (int t = 0; t < 4; t++) qv[t] = qg[p * 64 + t * 16 + ln];

    const float4 mp = pp4[ps];
#pragma unroll
    for (int j = 0; j < 16; j++) {
      // jj[j] is wave-uniform: readfirstlane -> uniform pointer -> s_load
      const int ju = __builtin_amdgcn_readfirstlane(jj[j]);
      const float4 np = pp4[ju];
      float h1 = fmaf(np.z - mp.z, pw12,
                 fmaf(np.y - mp.y, pw11,
                 fmaf(np.x - mp.x, pw10, pb1)));
      hm[j * 64 + HCOL(lane, j)] = f2bf(fmaxf(h1, 0.f));
    }
    f32x4 accp[4];
    mvl(hm, wlds, 0, bpe, ln, s0, s1, accp);       // posenc
    float vpe[4][4];
#pragma unroll
    for (int r = 0; r < 4; r++) {
      const int j = quad * 4 + r;
#pragma unroll
      for (int t = 0; t < 4; t++) {
        const unsigned w = kvw[r][t];
        float kf = __uint_as_float(w << 16);
        float vf = __uint_as_float(w & 0xFFFF0000u);
        float pe = accp[t][r];
        vpe[t][r] = vf + pe;
        hm[j * 64 + HCOL(t * 16 + ln, j)] = f2bf(qv[t] - kf + pe);
      }
    }
    f32x4 acch[4];
    mvl(hm, wlds, 1, ba1, ln, s0, s1, acch);       // hh @ at_w1 + b
#pragma unroll
    for (int t = 0; t < 4; t++)
#pragma unroll
      for (int r = 0; r < 4; r++) {
        const int j = quad * 4 + r;
        hm[j * 64 + HCOL(t * 16 + ln, j)] = f2bf(fmaxf(acch[t][r], 0.f));
      }
    f32x4 lg[4];
    mvl(hm, wlds, 2, ba2, ln, s0, s1, lg);         // logits
    const int pb = wid * 4 + pp;
#pragma unroll
    for (int t = 0; t < 4; t++) {                  // softmax (tiny logits)
      float e0 = __expf(lg[t][0] * 0.125f);
      float e1 = __expf(lg[t][1] * 0.125f);
      float e2 = __expf(lg[t][2] * 0.125f);
      float e3 = __expf(lg[t][3] * 0.125f);
      float ss = (e0 + e1) + (e2 + e3);
      float dt = fmaf(e3, vpe[t][3], fmaf(e2, vpe[t][2],
                 fmaf(e1, vpe[t][1], e0 * vpe[t][0])));
      ss += __shfl_xor(ss, 16); ss += __shfl_xor(ss, 32);
      dt += __shfl_xor(dt, 16); dt += __shfl_xor(dt, 32);
      float res = dt / ss;
      if (quad == 0) resm[pb * 64 + HCOL(t * 16 + ln, pb)] = f2bf(res);
    }
#pragma unroll
    for (int u = 0; u < 4; u++) cur[u] = nxt[u];
  }
  __syncthreads();
  {
    const int nt = wid;
    float ob = out_b[nt * 16 + ln];
    f32x4 acc = {ob, ob, ob, ob};
#pragma unroll
    for (int ks = 0; ks < 2; ks++) {
      bf16x8 a = *(const bf16x8*)(resm + ln * 64 +
                                  (((ks * 4 + quad + ln) & 7) << 3));
      acc = __builtin_amdgcn_mfma_f32_16x16x32_bf16(a, bo[ks], acc, 0, 0, 0);
    }
#pragma unroll
    for (int r = 0; r < 4; r++) {
      const int pt = blockIdx.x * 16 + quad * 4 + r;
      const int f = nt * 16 + ln;
      out[pt * 64 + f] = acc[r] + feat[pt * 64 + f];
    }
  }
}

// ============================ launcher ========================================
extern "C" void kernel_launch(void* const* d_in, const int* in_sizes, int n_in,
                              void* d_out, int out_size, void* d_ws, size_t ws_size,
                              hipStream_t stream)
{
  (void)in_sizes; (void)n_in; (void)out_size;
  const float* pos   = (const float*)d_in[0];
  const float* feat  = (const float*)d_in[1];
  const float* emb_w = (const float*)d_in[2];
  const float* emb_b = (const float*)d_in[3];
  const float* wq    = (const float*)d_in[4];
  const float* wk    = (const float*)d_in[5];
  const float* wv    = (const float*)d_in[6];
  const float* pe_w1 = (const float*)d_in[7];
  const float* pe_b1 = (const float*)d_in[8];
  const float* pe_w2 = (const float*)d_in[9];
  const float* pe_b2 = (const float*)d_in[10];
  const float* at_w1 = (const float*)d_in[11];
  const float* at_b1 = (const float*)d_in[12];
  const float* at_w2 = (const float*)d_in[13];
  const float* at_b2 = (const float*)d_in[14];
  const float* out_w = (const float*)d_in[15];
  const float* out_b = (const float*)d_in[16];
  float* ws = (float*)d_ws;

  // R20: runtime probe — wide (32-segment) KNN only if workspace fits part2.
  const bool wide = ws_size >= (size_t)WIDE_WORDS * 4u;
  if (wide) {
    mega1_t<32><<<2624, 256, 0, stream>>>(pos, feat, emb_w, emb_b, wq, wk, wv,
                                          pe_w2, at_w1, at_w2, out_w, ws);
    s3_merge_t<32><<<256, 64, 0, stream>>>(ws, (int*)ws + IDX_OFF);
  } else {
    mega1_t<16><<<1600, 256, 0, stream>>>(pos, feat, emb_w, emb_b, wq, wk, wv,
                                          pe_w2, at_w1, at_w2, out_w, ws);
    s3_merge_t<16><<<256, 64, 0, stream>>>(ws, (int*)ws + IDX_OFF);
  }
  s4_attn<<<NPTS / 16, 256, 0, stream>>>(ws, feat, pe_w1, pe_b1, pe_b2,
      at_b1, at_b2, out_b, (int*)ws + IDX_OFF, (float*)d_out);
}